// Round 1
// baseline (2123.756 us; speedup 1.0000x reference)
//
#include <hip/hip_runtime.h>

#define N_NODES 100000
#define N_EDGES 1250000
#define F_RAW 48
#define F_LOC 16
#define F1 48
#define F_IN1 64   // F_RAW + F_LOC
#define F_IN2 64   // F1 + F_LOC
#define F_OUT 64

// ---------------------------------------------------------------------------
// Edge-index dtype detection: reference requests int64; if JAX x64 was off the
// buffer is int32. For int64 little-endian values < 2^31, every odd 32-bit
// word is 0. With random src values in [0, 1e5), odd words being all-zero for
// int32 data has probability ~(1e-5)^2048 ~ 0. flag=1 -> int32, flag=0 -> int64.
// ---------------------------------------------------------------------------
__global__ void k_detect(const unsigned* edges_u32, int* flag) {
    __shared__ int any;
    if (threadIdx.x == 0) any = 0;
    __syncthreads();
    int nz = 0;
    for (int i = threadIdx.x; i < 2048; i += 256) {
        if (edges_u32[2 * i + 1] != 0u) nz = 1;
    }
    if (nz) atomicOr(&any, 1);
    __syncthreads();
    if (threadIdx.x == 0) *flag = any;
}

__device__ __forceinline__ void load_edge(const void* edges, int is32, int e,
                                          int& s, int& d) {
    if (is32) {
        const int* p = (const int*)edges;
        s = p[e];
        d = p[N_EDGES + e];
    } else {
        const long long* p = (const long long*)edges;
        s = (int)p[e];
        d = (int)p[N_EDGES + e];
    }
}

// deg[dst] += 1 per edge
__global__ void k_deg(const void* edges, const int* flag, float* deg) {
    int e = blockIdx.x * blockDim.x + threadIdx.x;
    if (e >= N_EDGES) return;
    int is32 = *flag;
    int s, d;
    load_edge(edges, is32, e, s, d);
    (void)s;
    atomicAdd(&deg[d], 1.0f);
}

// deg -> rsqrt(deg + 1) in place
__global__ void k_dinv(float* deg) {
    int i = blockIdx.x * blockDim.x + threadIdx.x;
    if (i < N_NODES) deg[i] = rsqrtf(deg[i] + 1.0f);
}

// h1 = [feat, loc] @ W1   (one wave per node, W1 in LDS)
__global__ __launch_bounds__(256) void k_h1(const float* __restrict__ feat,
                                            const float* __restrict__ loc,
                                            const float* __restrict__ W1,
                                            float* __restrict__ h1) {
    __shared__ float sW[F_IN1 * F1 + 64];  // pad so lanes 48..63 can read junk
    for (int i = threadIdx.x; i < F_IN1 * F1; i += 256) sW[i] = W1[i];
    __syncthreads();
    int wave = threadIdx.x >> 6;
    int lane = threadIdx.x & 63;
    int node = blockIdx.x * 4 + wave;
    if (node >= N_NODES) return;
    float xl = (lane < F_RAW) ? feat[node * F_RAW + lane]
                              : loc[node * F_LOC + (lane - F_RAW)];
    float acc = 0.f;
#pragma unroll
    for (int k = 0; k < F_IN1; ++k) {
        float xk = __shfl(xl, k);
        acc = fmaf(xk, sW[k * F1 + lane], acc);  // lanes >=48 compute junk
    }
    if (lane < F1) h1[node * F1 + lane] = acc;
}

// agg1[dst] += h1[src] * dinv[src]*dinv[dst]; thread per (edge, float4 chunk)
__global__ void k_scatter1(const void* edges, const int* flag,
                           const float* __restrict__ dinv,
                           const float* __restrict__ h1,
                           float* __restrict__ agg1) {
    const int per = F1 / 4;  // 12
    int idx = blockIdx.x * blockDim.x + threadIdx.x;
    if (idx >= N_EDGES * per) return;
    int e = idx / per;
    int q = idx - e * per;
    int is32 = *flag;
    int s, d;
    load_edge(edges, is32, e, s, d);
    float c = dinv[s] * dinv[d];
    float4 v = reinterpret_cast<const float4*>(h1)[s * per + q];
    float* a = agg1 + (size_t)d * F1 + q * 4;
    atomicAdd(a + 0, v.x * c);
    atomicAdd(a + 1, v.y * c);
    atomicAdd(a + 2, v.z * c);
    atomicAdd(a + 3, v.w * c);
}

// x1 = relu(agg1 + h1*dinv^2 + b1); h2 = [x1, loc] @ W2;
// out = h2*dinv^2 + b2  (self-loop + bias init; scatter2 adds the rest)
__global__ __launch_bounds__(256) void k_mid(const float* __restrict__ h1,
                                             const float* __restrict__ agg1,
                                             const float* __restrict__ dinv,
                                             const float* __restrict__ loc,
                                             const float* __restrict__ W2,
                                             const float* __restrict__ b1,
                                             const float* __restrict__ b2,
                                             float* __restrict__ h2,
                                             float* __restrict__ out) {
    __shared__ float sW[F_IN2 * F_OUT];  // 16 KB
    for (int i = threadIdx.x; i < F_IN2 * F_OUT; i += 256) sW[i] = W2[i];
    __syncthreads();
    int wave = threadIdx.x >> 6;
    int lane = threadIdx.x & 63;
    int node = blockIdx.x * 4 + wave;
    if (node >= N_NODES) return;
    float di = dinv[node];
    float d2 = di * di;
    float xl;
    if (lane < F1) {
        float v = agg1[node * F1 + lane] + h1[node * F1 + lane] * d2 + b1[lane];
        xl = v > 0.f ? v : 0.f;
    } else {
        xl = loc[node * F_LOC + (lane - F1)];
    }
    float acc = 0.f;
#pragma unroll
    for (int k = 0; k < F_IN2; ++k) {
        float xk = __shfl(xl, k);
        acc = fmaf(xk, sW[k * F_OUT + lane], acc);
    }
    h2[node * F_OUT + lane] = acc;
    out[node * F_OUT + lane] = acc * d2 + b2[lane];
}

// out[dst] += h2[src] * dinv[src]*dinv[dst]; thread per (edge, float4 chunk)
__global__ void k_scatter2(const void* edges, const int* flag,
                           const float* __restrict__ dinv,
                           const float* __restrict__ h2,
                           float* __restrict__ out) {
    const int per = F_OUT / 4;  // 16
    int idx = blockIdx.x * blockDim.x + threadIdx.x;
    if (idx >= N_EDGES * per) return;
    int e = idx >> 4;
    int q = idx & 15;
    int is32 = *flag;
    int s, d;
    load_edge(edges, is32, e, s, d);
    float c = dinv[s] * dinv[d];
    float4 v = reinterpret_cast<const float4*>(h2)[s * per + q];
    float* a = out + (size_t)d * F_OUT + q * 4;
    atomicAdd(a + 0, v.x * c);
    atomicAdd(a + 1, v.y * c);
    atomicAdd(a + 2, v.z * c);
    atomicAdd(a + 3, v.w * c);
}

extern "C" void kernel_launch(void* const* d_in, const int* in_sizes, int n_in,
                              void* d_out, int out_size, void* d_ws,
                              size_t ws_size, hipStream_t stream) {
    const void* edges = d_in[0];
    const float* feat = (const float*)d_in[1];
    const float* loc = (const float*)d_in[2];
    const float* W1 = (const float*)d_in[3];
    const float* b1 = (const float*)d_in[4];
    const float* W2 = (const float*)d_in[5];
    const float* b2 = (const float*)d_in[6];
    float* out = (float*)d_out;

    char* ws = (char*)d_ws;
    // ws layout (bytes), all 16-aligned:
    float* dinv = (float*)(ws + 0);                    // 400,000
    float* h1 = (float*)(ws + 400000);                 // 19,200,000
    float* agg1 = (float*)(ws + 19600000);             // 19,200,000
    float* h2 = (float*)(ws + 38800000);               // 25,600,000
    int* flag = (int*)(ws + 64400000);                 // 4

    k_detect<<<1, 256, 0, stream>>>((const unsigned*)edges, flag);
    hipMemsetAsync(dinv, 0, (size_t)N_NODES * 4, stream);
    hipMemsetAsync(agg1, 0, (size_t)N_NODES * F1 * 4, stream);

    k_deg<<<(N_EDGES + 255) / 256, 256, 0, stream>>>(edges, flag, dinv);
    k_dinv<<<(N_NODES + 255) / 256, 256, 0, stream>>>(dinv);
    k_h1<<<(N_NODES + 3) / 4, 256, 0, stream>>>(feat, loc, W1, h1);

    int t1 = N_EDGES * (F1 / 4);  // 15,000,000
    k_scatter1<<<(t1 + 255) / 256, 256, 0, stream>>>(edges, flag, dinv, h1,
                                                     agg1);
    k_mid<<<(N_NODES + 3) / 4, 256, 0, stream>>>(h1, agg1, dinv, loc, W2, b1,
                                                 b2, h2, out);
    int t2 = N_EDGES * (F_OUT / 4);  // 20,000,000
    k_scatter2<<<(t2 + 255) / 256, 256, 0, stream>>>(edges, flag, dinv, h2,
                                                     out);
}

// Round 2
// 686.097 us; speedup vs baseline: 3.0954x; 3.0954x over previous
//
#include <hip/hip_runtime.h>

#define N_NODES 100000
#define N_EDGES 1250000
#define F_RAW 48
#define F_LOC 16
#define F1 48
#define F_IN1 64   // F_RAW + F_LOC
#define F_IN2 64   // F1 + F_LOC
#define F_OUT 64

// ---------------------------------------------------------------------------
// Edge-index dtype detection (int64 vs int32 buffer), as before.
// ---------------------------------------------------------------------------
__global__ void k_detect(const unsigned* edges_u32, int* flag) {
    __shared__ int any;
    if (threadIdx.x == 0) any = 0;
    __syncthreads();
    int nz = 0;
    for (int i = threadIdx.x; i < 2048; i += 256) {
        if (edges_u32[2 * i + 1] != 0u) nz = 1;
    }
    if (nz) atomicOr(&any, 1);
    __syncthreads();
    if (threadIdx.x == 0) *flag = any;
}

__device__ __forceinline__ void load_edge(const void* edges, int is32, int e,
                                          int& s, int& d) {
    if (is32) {
        const int* p = (const int*)edges;
        s = p[e];
        d = p[N_EDGES + e];
    } else {
        const long long* p = (const long long*)edges;
        s = (int)p[e];
        d = (int)p[N_EDGES + e];
    }
}

// deg[dst] += 1 (int histogram)
__global__ void k_deg(const void* edges, const int* flag, int* deg) {
    int e = blockIdx.x * blockDim.x + threadIdx.x;
    if (e >= N_EDGES) return;
    int s, d;
    load_edge(edges, *flag, e, s, d);
    (void)s;
    atomicAdd(&deg[d], 1);
}

// dinv = rsqrt(deg + 1)
__global__ void k_dinv(const int* __restrict__ deg, float* __restrict__ dinv) {
    int i = blockIdx.x * blockDim.x + threadIdx.x;
    if (i < N_NODES) dinv[i] = rsqrtf((float)deg[i] + 1.0f);
}

// exclusive prefix sum of deg -> rowptr (single block, 1024 threads)
__global__ __launch_bounds__(1024) void k_scan(const int* __restrict__ deg,
                                               int* __restrict__ rowptr) {
    __shared__ int tsum[1024];
    int t = threadIdx.x;
    const int chunk = (N_NODES + 1023) / 1024;  // 98
    int lo = t * chunk;
    int hi = lo + chunk;
    if (hi > N_NODES) hi = N_NODES;
    int s = 0;
    for (int i = lo; i < hi; ++i) s += deg[i];
    tsum[t] = s;
    __syncthreads();
    // Hillis-Steele inclusive scan over 1024 partial sums
    for (int off = 1; off < 1024; off <<= 1) {
        int v = (t >= off) ? tsum[t - off] : 0;
        __syncthreads();
        tsum[t] += v;
        __syncthreads();
    }
    int run = (t == 0) ? 0 : tsum[t - 1];  // exclusive prefix of this chunk
    for (int i = lo; i < hi; ++i) {
        rowptr[i] = run;
        run += deg[i];
    }
    if (t == 1023) rowptr[N_NODES] = run;  // == N_EDGES
}

// fill CSR: csr_src[pos], csr_coef[pos] grouped by dst
__global__ void k_fill(const void* edges, const int* flag,
                       const float* __restrict__ dinv,
                       const int* __restrict__ rowptr, int* __restrict__ cnt,
                       int* __restrict__ csr_src,
                       float* __restrict__ csr_coef) {
    int e = blockIdx.x * blockDim.x + threadIdx.x;
    if (e >= N_EDGES) return;
    int s, d;
    load_edge(edges, *flag, e, s, d);
    int pos = rowptr[d] + atomicAdd(&cnt[d], 1);
    csr_src[pos] = s;
    csr_coef[pos] = dinv[s] * dinv[d];
}

// h1 = [feat, loc] @ W1   (one wave per node, W1 in LDS)
__global__ __launch_bounds__(256) void k_h1(const float* __restrict__ feat,
                                            const float* __restrict__ loc,
                                            const float* __restrict__ W1,
                                            float* __restrict__ h1) {
    __shared__ float sW[F_IN1 * F1 + 64];
    for (int i = threadIdx.x; i < F_IN1 * F1; i += 256) sW[i] = W1[i];
    __syncthreads();
    int wave = threadIdx.x >> 6;
    int lane = threadIdx.x & 63;
    int node = blockIdx.x * 4 + wave;
    if (node >= N_NODES) return;
    float xl = (lane < F_RAW) ? feat[node * F_RAW + lane]
                              : loc[node * F_LOC + (lane - F_RAW)];
    float acc = 0.f;
#pragma unroll
    for (int k = 0; k < F_IN1; ++k) {
        float xk = __shfl(xl, k);
        acc = fmaf(xk, sW[k * F1 + lane], acc);
    }
    if (lane < F1) h1[node * F1 + lane] = acc;
}

// fused: agg1 (gather) + self-loop + bias + relu + GEMM W2 -> h2
__global__ __launch_bounds__(256) void k_mid(
    const float* __restrict__ h1, const float* __restrict__ dinv,
    const int* __restrict__ rowptr, const int* __restrict__ csr_src,
    const float* __restrict__ csr_coef, const float* __restrict__ loc,
    const float* __restrict__ W2, const float* __restrict__ b1,
    float* __restrict__ h2) {
    __shared__ float sW[F_IN2 * F_OUT];  // 16 KB
    for (int i = threadIdx.x; i < F_IN2 * F_OUT; i += 256) sW[i] = W2[i];
    __syncthreads();
    int wave = threadIdx.x >> 6;
    int lane = threadIdx.x & 63;
    int node = blockIdx.x * 4 + wave;
    if (node >= N_NODES) return;
    float di = dinv[node];
    float d2 = di * di;
    int r0 = rowptr[node], r1 = rowptr[node + 1];
    float xl;
    if (lane < F1) {
        float acc = h1[node * F1 + lane] * d2;
        for (int e = r0; e < r1; ++e) {
            int s = csr_src[e];
            float c = csr_coef[e];
            acc = fmaf(h1[s * F1 + lane], c, acc);
        }
        acc += b1[lane];
        xl = acc > 0.f ? acc : 0.f;
    } else {
        xl = loc[node * F_LOC + (lane - F1)];
    }
    float accv = 0.f;
#pragma unroll
    for (int k = 0; k < F_IN2; ++k) {
        float xk = __shfl(xl, k);
        accv = fmaf(xk, sW[k * F_OUT + lane], accv);
    }
    h2[node * F_OUT + lane] = accv;
}

// fused: agg2 (gather) + self-loop + bias -> out
__global__ __launch_bounds__(256) void k_out(
    const float* __restrict__ h2, const float* __restrict__ dinv,
    const int* __restrict__ rowptr, const int* __restrict__ csr_src,
    const float* __restrict__ csr_coef, const float* __restrict__ b2,
    float* __restrict__ out) {
    int wave = threadIdx.x >> 6;
    int lane = threadIdx.x & 63;
    int node = blockIdx.x * 4 + wave;
    if (node >= N_NODES) return;
    float di = dinv[node];
    float d2 = di * di;
    int r0 = rowptr[node], r1 = rowptr[node + 1];
    float acc = h2[node * F_OUT + lane] * d2 + b2[lane];
    for (int e = r0; e < r1; ++e) {
        int s = csr_src[e];
        float c = csr_coef[e];
        acc = fmaf(h2[s * F_OUT + lane], c, acc);
    }
    out[node * F_OUT + lane] = acc;
}

extern "C" void kernel_launch(void* const* d_in, const int* in_sizes, int n_in,
                              void* d_out, int out_size, void* d_ws,
                              size_t ws_size, hipStream_t stream) {
    const void* edges = d_in[0];
    const float* feat = (const float*)d_in[1];
    const float* loc = (const float*)d_in[2];
    const float* W1 = (const float*)d_in[3];
    const float* b1 = (const float*)d_in[4];
    const float* W2 = (const float*)d_in[5];
    const float* b2 = (const float*)d_in[6];
    float* out = (float*)d_out;

    char* ws = (char*)d_ws;
    // ws layout (bytes):
    float* dinv = (float*)(ws + 0);            //   400,000
    int* deg = (int*)(ws + 400000);            //   400,000 (reused as cnt)
    int* rowptr = (int*)(ws + 800000);         //   400,004
    int* csr_src = (int*)(ws + 1200512);       // 5,000,000
    float* csr_coef = (float*)(ws + 6200512);  // 5,000,000
    float* h1 = (float*)(ws + 11200512);       // 19,200,000
    float* h2 = (float*)(ws + 30400512);       // 25,600,000
    int* flag = (int*)(ws + 56000512);         // 4

    k_detect<<<1, 256, 0, stream>>>((const unsigned*)edges, flag);
    hipMemsetAsync(deg, 0, (size_t)N_NODES * 4, stream);
    k_deg<<<(N_EDGES + 255) / 256, 256, 0, stream>>>(edges, flag, deg);
    k_dinv<<<(N_NODES + 255) / 256, 256, 0, stream>>>(deg, dinv);
    k_scan<<<1, 1024, 0, stream>>>(deg, rowptr);
    hipMemsetAsync(deg, 0, (size_t)N_NODES * 4, stream);  // now edge counters
    k_fill<<<(N_EDGES + 255) / 256, 256, 0, stream>>>(edges, flag, dinv,
                                                      rowptr, deg, csr_src,
                                                      csr_coef);
    k_h1<<<(N_NODES + 3) / 4, 256, 0, stream>>>(feat, loc, W1, h1);
    k_mid<<<(N_NODES + 3) / 4, 256, 0, stream>>>(h1, dinv, rowptr, csr_src,
                                                 csr_coef, loc, W2, b1, h2);
    k_out<<<(N_NODES + 3) / 4, 256, 0, stream>>>(h2, dinv, rowptr, csr_src,
                                                 csr_coef, b2, out);
}

// Round 3
// 668.831 us; speedup vs baseline: 3.1753x; 1.0258x over previous
//
#include <hip/hip_runtime.h>

#define N_NODES 100000
#define N_EDGES 1250000
#define F_RAW 48
#define F_LOC 16
#define F1 48
#define F_IN1 64   // F_RAW + F_LOC
#define F_IN2 64   // F1 + F_LOC
#define F_OUT 64

// ---------------------------------------------------------------------------
// Edge-index dtype detection (int64 vs int32 buffer).
// ---------------------------------------------------------------------------
__global__ void k_detect(const unsigned* edges_u32, int* flag) {
    __shared__ int any;
    if (threadIdx.x == 0) any = 0;
    __syncthreads();
    int nz = 0;
    for (int i = threadIdx.x; i < 2048; i += 256) {
        if (edges_u32[2 * i + 1] != 0u) nz = 1;
    }
    if (nz) atomicOr(&any, 1);
    __syncthreads();
    if (threadIdx.x == 0) *flag = any;
}

__device__ __forceinline__ void load_edge(const void* edges, int is32, int e,
                                          int& s, int& d) {
    if (is32) {
        const int* p = (const int*)edges;
        s = p[e];
        d = p[N_EDGES + e];
    } else {
        const long long* p = (const long long*)edges;
        s = (int)p[e];
        d = (int)p[N_EDGES + e];
    }
}

// deg[dst] += 1 (int histogram)
__global__ void k_deg(const void* edges, const int* flag, int* deg) {
    int e = blockIdx.x * blockDim.x + threadIdx.x;
    if (e >= N_EDGES) return;
    int s, d;
    load_edge(edges, *flag, e, s, d);
    (void)s;
    atomicAdd(&deg[d], 1);
}

// dinv = rsqrt(deg + 1)
__global__ void k_dinv(const int* __restrict__ deg, float* __restrict__ dinv) {
    int i = blockIdx.x * blockDim.x + threadIdx.x;
    if (i < N_NODES) dinv[i] = rsqrtf((float)deg[i] + 1.0f);
}

// exclusive prefix sum of deg -> rowptr AND cnt (slot counters pre-seeded)
__global__ __launch_bounds__(1024) void k_scan(const int* __restrict__ deg,
                                               int* __restrict__ rowptr,
                                               int* __restrict__ cnt) {
    __shared__ int tsum[1024];
    int t = threadIdx.x;
    const int chunk = (N_NODES + 1023) / 1024;  // 98
    int lo = t * chunk;
    int hi = lo + chunk;
    if (hi > N_NODES) hi = N_NODES;
    int s = 0;
    for (int i = lo; i < hi; ++i) s += deg[i];
    tsum[t] = s;
    __syncthreads();
    for (int off = 1; off < 1024; off <<= 1) {
        int v = (t >= off) ? tsum[t - off] : 0;
        __syncthreads();
        tsum[t] += v;
        __syncthreads();
    }
    int run = (t == 0) ? 0 : tsum[t - 1];
    for (int i = lo; i < hi; ++i) {
        rowptr[i] = run;
        cnt[i] = run;
        run += deg[i];
    }
    if (t == 1023) rowptr[N_NODES] = run;
}

// fill CSR entries (src, dinv[src]) grouped by dst; cnt pre-seeded w/ rowptr
__global__ void k_fill(const void* edges, const int* flag,
                       const float* __restrict__ dinv, int* __restrict__ cnt,
                       int2* __restrict__ csr) {
    int e = blockIdx.x * blockDim.x + threadIdx.x;
    if (e >= N_EDGES) return;
    int s, d;
    load_edge(edges, *flag, e, s, d);
    int pos = atomicAdd(&cnt[d], 1);
    csr[pos] = make_int2(s, __float_as_int(dinv[s]));
}

// h1 = [feat, loc] @ W1   (one wave per node, W1 in LDS)
__global__ __launch_bounds__(256) void k_h1(const float* __restrict__ feat,
                                            const float* __restrict__ loc,
                                            const float* __restrict__ W1,
                                            float* __restrict__ h1) {
    __shared__ float sW[F_IN1 * F1 + 64];
    for (int i = threadIdx.x; i < F_IN1 * F1; i += 256) sW[i] = W1[i];
    __syncthreads();
    int wave = threadIdx.x >> 6;
    int lane = threadIdx.x & 63;
    int node = blockIdx.x * 4 + wave;
    if (node >= N_NODES) return;
    float xl = (lane < F_RAW) ? feat[node * F_RAW + lane]
                              : loc[node * F_LOC + (lane - F_RAW)];
    float acc = 0.f;
#pragma unroll
    for (int k = 0; k < F_IN1; ++k) {
        float xk = __shfl(xl, k);
        acc = fmaf(xk, sW[k * F1 + lane], acc);
    }
    if (lane < F1) h1[node * F1 + lane] = acc;
}

__device__ __forceinline__ float4 xor4(float4 v, int m) {
    v.x += __shfl_xor(v.x, m);
    v.y += __shfl_xor(v.y, m);
    v.z += __shfl_xor(v.z, m);
    v.w += __shfl_xor(v.w, m);
    return v;
}

// fused: agg1 (4-edge-group float4 gather) + self + bias + relu + GEMM W2 -> h2
__global__ __launch_bounds__(256) void k_mid(
    const float* __restrict__ h1, const float* __restrict__ dinv,
    const int* __restrict__ rowptr, const int2* __restrict__ csr,
    const float* __restrict__ loc, const float* __restrict__ W2,
    const float* __restrict__ b1, float* __restrict__ h2) {
    __shared__ float sW[F_IN2 * F_OUT];  // 16 KB
    for (int i = threadIdx.x; i < F_IN2 * F_OUT; i += 256) sW[i] = W2[i];
    __syncthreads();
    int wave = threadIdx.x >> 6;
    int lane = threadIdx.x & 63;
    int grp = lane >> 4;    // 4 edge groups
    int l4 = lane & 15;     // float4 slot within row (12 used for F1=48)
    int node = blockIdx.x * 4 + wave;
    if (node >= N_NODES) return;
    int r0 = rowptr[node], r1 = rowptr[node + 1];
    float4 acc = make_float4(0.f, 0.f, 0.f, 0.f);
    for (int e = r0 + grp; e < r1; e += 4) {
        int2 ent = csr[e];
        float c = __int_as_float(ent.y);
        if (l4 < 12) {
            float4 v =
                reinterpret_cast<const float4*>(h1 + (size_t)ent.x * F1)[l4];
            acc.x = fmaf(v.x, c, acc.x);
            acc.y = fmaf(v.y, c, acc.y);
            acc.z = fmaf(v.z, c, acc.z);
            acc.w = fmaf(v.w, c, acc.w);
        }
    }
    acc = xor4(acc, 16);
    acc = xor4(acc, 32);
    float di = dinv[node];
    float d2 = di * di;
    float4 x4 = make_float4(0.f, 0.f, 0.f, 0.f);
    if (l4 < 12) {
        float4 hs = reinterpret_cast<const float4*>(h1 + (size_t)node * F1)[l4];
        float4 b4 = reinterpret_cast<const float4*>(b1)[l4];
        x4.x = fmaxf(fmaf(acc.x, di, fmaf(hs.x, d2, b4.x)), 0.f);
        x4.y = fmaxf(fmaf(acc.y, di, fmaf(hs.y, d2, b4.y)), 0.f);
        x4.z = fmaxf(fmaf(acc.z, di, fmaf(hs.z, d2, b4.z)), 0.f);
        x4.w = fmaxf(fmaf(acc.w, di, fmaf(hs.w, d2, b4.w)), 0.f);
    }
    float locv = (lane >= F1) ? loc[node * F_LOC + (lane - F1)] : 0.f;
    float accv = 0.f;
#pragma unroll
    for (int k = 0; k < F1; ++k) {
        float comp = (k & 3) == 0   ? x4.x
                     : (k & 3) == 1 ? x4.y
                     : (k & 3) == 2 ? x4.z
                                    : x4.w;
        float xk = __shfl(comp, k >> 2);
        accv = fmaf(xk, sW[k * F_OUT + lane], accv);
    }
#pragma unroll
    for (int k = F1; k < F_IN2; ++k) {
        float xk = __shfl(locv, k);
        accv = fmaf(xk, sW[k * F_OUT + lane], accv);
    }
    h2[node * F_OUT + lane] = accv;
}

// fused: agg2 (4-edge-group float4 gather) + self + bias -> out
__global__ __launch_bounds__(256) void k_out(
    const float* __restrict__ h2, const float* __restrict__ dinv,
    const int* __restrict__ rowptr, const int2* __restrict__ csr,
    const float* __restrict__ b2, float* __restrict__ out) {
    int wave = threadIdx.x >> 6;
    int lane = threadIdx.x & 63;
    int grp = lane >> 4;
    int l4 = lane & 15;  // all 16 slots used (F_OUT=64)
    int node = blockIdx.x * 4 + wave;
    if (node >= N_NODES) return;
    int r0 = rowptr[node], r1 = rowptr[node + 1];
    float4 acc = make_float4(0.f, 0.f, 0.f, 0.f);
    for (int e = r0 + grp; e < r1; e += 4) {
        int2 ent = csr[e];
        float c = __int_as_float(ent.y);
        float4 v =
            reinterpret_cast<const float4*>(h2 + (size_t)ent.x * F_OUT)[l4];
        acc.x = fmaf(v.x, c, acc.x);
        acc.y = fmaf(v.y, c, acc.y);
        acc.z = fmaf(v.z, c, acc.z);
        acc.w = fmaf(v.w, c, acc.w);
    }
    acc = xor4(acc, 16);
    acc = xor4(acc, 32);
    if (lane < 16) {
        float di = dinv[node];
        float d2 = di * di;
        float4 hs = reinterpret_cast<const float4*>(h2 + (size_t)node * F_OUT)[l4];
        float4 b4 = reinterpret_cast<const float4*>(b2)[l4];
        float4 o;
        o.x = fmaf(acc.x, di, fmaf(hs.x, d2, b4.x));
        o.y = fmaf(acc.y, di, fmaf(hs.y, d2, b4.y));
        o.z = fmaf(acc.z, di, fmaf(hs.z, d2, b4.z));
        o.w = fmaf(acc.w, di, fmaf(hs.w, d2, b4.w));
        reinterpret_cast<float4*>(out + (size_t)node * F_OUT)[l4] = o;
    }
}

extern "C" void kernel_launch(void* const* d_in, const int* in_sizes, int n_in,
                              void* d_out, int out_size, void* d_ws,
                              size_t ws_size, hipStream_t stream) {
    const void* edges = d_in[0];
    const float* feat = (const float*)d_in[1];
    const float* loc = (const float*)d_in[2];
    const float* W1 = (const float*)d_in[3];
    const float* b1 = (const float*)d_in[4];
    const float* W2 = (const float*)d_in[5];
    const float* b2 = (const float*)d_in[6];
    float* out = (float*)d_out;

    char* ws = (char*)d_ws;
    float* dinv = (float*)(ws + 0);         //   400,000
    int* deg = (int*)(ws + 400000);         //   400,000
    int* rowptr = (int*)(ws + 800000);      //   400,016 (incl pad)
    int* cnt = (int*)(ws + 1200016);        //   400,000
    int2* csr = (int2*)(ws + 1600016);      // 10,000,000
    float* h1 = (float*)(ws + 11600016);    // 19,200,000
    float* h2 = (float*)(ws + 30800016);    // 25,600,000
    int* flag = (int*)(ws + 56400016);      // 4

    k_detect<<<1, 256, 0, stream>>>((const unsigned*)edges, flag);
    hipMemsetAsync(deg, 0, (size_t)N_NODES * 4, stream);
    k_deg<<<(N_EDGES + 255) / 256, 256, 0, stream>>>(edges, flag, deg);
    k_dinv<<<(N_NODES + 255) / 256, 256, 0, stream>>>(deg, dinv);
    k_scan<<<1, 1024, 0, stream>>>(deg, rowptr, cnt);
    k_fill<<<(N_EDGES + 255) / 256, 256, 0, stream>>>(edges, flag, dinv, cnt,
                                                      csr);
    k_h1<<<(N_NODES + 3) / 4, 256, 0, stream>>>(feat, loc, W1, h1);
    k_mid<<<(N_NODES + 3) / 4, 256, 0, stream>>>(h1, dinv, rowptr, csr, loc,
                                                 W2, b1, h2);
    k_out<<<(N_NODES + 3) / 4, 256, 0, stream>>>(h2, dinv, rowptr, csr, b2,
                                                 out);
}

// Round 4
// 448.633 us; speedup vs baseline: 4.7338x; 1.4908x over previous
//
#include <hip/hip_runtime.h>

#define N_NODES 100000
#define N_EDGES 1250000
#define F_RAW 48
#define F_LOC 16
#define F1 48
#define F_IN1 64   // F_RAW + F_LOC
#define F_IN2 64   // F1 + F_LOC
#define F_OUT 64

#define SCAN_SEG 1024
#define SCAN_NB ((N_NODES + SCAN_SEG - 1) / SCAN_SEG)  // 98

// ---------------------------------------------------------------------------
// Edge-index dtype detection (int64 vs int32 buffer).
// ---------------------------------------------------------------------------
__global__ void k_detect(const unsigned* edges_u32, int* flag) {
    __shared__ int any;
    if (threadIdx.x == 0) any = 0;
    __syncthreads();
    int nz = 0;
    for (int i = threadIdx.x; i < 2048; i += 256) {
        if (edges_u32[2 * i + 1] != 0u) nz = 1;
    }
    if (nz) atomicOr(&any, 1);
    __syncthreads();
    if (threadIdx.x == 0) *flag = any;
}

__device__ __forceinline__ void load_edge(const void* edges, int is32, int e,
                                          int& s, int& d) {
    if (is32) {
        const int* p = (const int*)edges;
        s = p[e];
        d = p[N_EDGES + e];
    } else {
        const long long* p = (const long long*)edges;
        s = (int)p[e];
        d = (int)p[N_EDGES + e];
    }
}

// deg[dst] += 1 (int histogram)
__global__ void k_deg(const void* edges, const int* flag, int* deg) {
    int e = blockIdx.x * blockDim.x + threadIdx.x;
    if (e >= N_EDGES) return;
    int s, d;
    load_edge(edges, *flag, e, s, d);
    (void)s;
    atomicAdd(&deg[d], 1);
}

// --------------------------- hierarchical scan ------------------------------
// phase 1: per-block (1024 elems) sums
__global__ __launch_bounds__(256) void k_scan_part(const int* __restrict__ deg,
                                                   int* __restrict__ bsum) {
    int b = blockIdx.x;
    int t = threadIdx.x;
    int i0 = b * SCAN_SEG + t * 4;
    int s = 0;
#pragma unroll
    for (int j = 0; j < 4; ++j) {
        int i = i0 + j;
        if (i < N_NODES) s += deg[i];
    }
#pragma unroll
    for (int m = 1; m < 64; m <<= 1) s += __shfl_xor(s, m);
    __shared__ int ws[4];
    if ((t & 63) == 0) ws[t >> 6] = s;
    __syncthreads();
    if (t == 0) bsum[b] = ws[0] + ws[1] + ws[2] + ws[3];
}

// phase 2: exclusive scan of the 98 block sums (single tiny block)
__global__ __launch_bounds__(128) void k_scan_top(int* __restrict__ bsum,
                                                  int* __restrict__ rowptr) {
    __shared__ int sh[128];
    int t = threadIdx.x;
    int v = (t < SCAN_NB) ? bsum[t] : 0;
    sh[t] = v;
    __syncthreads();
    for (int off = 1; off < 128; off <<= 1) {
        int u = (t >= off) ? sh[t - off] : 0;
        __syncthreads();
        sh[t] += u;
        __syncthreads();
    }
    if (t < SCAN_NB) bsum[t] = (t == 0) ? 0 : sh[t - 1];
    if (t == 127) rowptr[N_NODES] = sh[127];
}

// phase 3: downsweep -> rowptr, cnt (slot counters), dinv
__global__ __launch_bounds__(256) void k_scan_down(
    const int* __restrict__ deg, const int* __restrict__ bsum,
    int* __restrict__ rowptr, int* __restrict__ cnt,
    float* __restrict__ dinv) {
    int b = blockIdx.x;
    int t = threadIdx.x;
    int lane = t & 63;
    int wave = t >> 6;
    int i0 = b * SCAN_SEG + t * 4;
    int v[4];
    int s = 0;
#pragma unroll
    for (int j = 0; j < 4; ++j) {
        int i = i0 + j;
        v[j] = (i < N_NODES) ? deg[i] : 0;
        s += v[j];
    }
    int x = s;
#pragma unroll
    for (int off = 1; off < 64; off <<= 1) {
        int u = __shfl_up(x, off);
        if (lane >= off) x += u;
    }
    __shared__ int ws[4];
    if (lane == 63) ws[wave] = x;
    __syncthreads();
    int woff = 0;
    for (int w = 0; w < wave; ++w) woff += ws[w];
    int run = bsum[b] + woff + (x - s);
#pragma unroll
    for (int j = 0; j < 4; ++j) {
        int i = i0 + j;
        if (i < N_NODES) {
            rowptr[i] = run;
            cnt[i] = run;
            dinv[i] = rsqrtf((float)v[j] + 1.0f);
            run += v[j];
        }
    }
}

// fill CSR entries (src, dinv[src]) grouped by dst; cnt pre-seeded w/ rowptr
__global__ void k_fill(const void* edges, const int* flag,
                       const float* __restrict__ dinv, int* __restrict__ cnt,
                       int2* __restrict__ csr) {
    int e = blockIdx.x * blockDim.x + threadIdx.x;
    if (e >= N_EDGES) return;
    int s, d;
    load_edge(edges, *flag, e, s, d);
    int pos = atomicAdd(&cnt[d], 1);
    csr[pos] = make_int2(s, __float_as_int(dinv[s]));
}

// h1 = [feat, loc] @ W1   (one wave per node, W1 in LDS)
__global__ __launch_bounds__(256) void k_h1(const float* __restrict__ feat,
                                            const float* __restrict__ loc,
                                            const float* __restrict__ W1,
                                            float* __restrict__ h1) {
    __shared__ float sW[F_IN1 * F1 + 64];
    for (int i = threadIdx.x; i < F_IN1 * F1; i += 256) sW[i] = W1[i];
    __syncthreads();
    int wave = threadIdx.x >> 6;
    int lane = threadIdx.x & 63;
    int node = blockIdx.x * 4 + wave;
    if (node >= N_NODES) return;
    float xl = (lane < F_RAW) ? feat[node * F_RAW + lane]
                              : loc[node * F_LOC + (lane - F_RAW)];
    float acc = 0.f;
#pragma unroll
    for (int k = 0; k < F_IN1; ++k) {
        float xk = __shfl(xl, k);
        acc = fmaf(xk, sW[k * F1 + lane], acc);
    }
    if (lane < F1) h1[node * F1 + lane] = acc;
}

__device__ __forceinline__ float4 xor4(float4 v, int m) {
    v.x += __shfl_xor(v.x, m);
    v.y += __shfl_xor(v.y, m);
    v.z += __shfl_xor(v.z, m);
    v.w += __shfl_xor(v.w, m);
    return v;
}

// fused: agg1 (4-edge-group float4 gather) + self + bias + relu + GEMM W2 -> h2
__global__ __launch_bounds__(256) void k_mid(
    const float* __restrict__ h1, const float* __restrict__ dinv,
    const int* __restrict__ rowptr, const int2* __restrict__ csr,
    const float* __restrict__ loc, const float* __restrict__ W2,
    const float* __restrict__ b1, float* __restrict__ h2) {
    __shared__ float sW[F_IN2 * F_OUT];  // 16 KB
    for (int i = threadIdx.x; i < F_IN2 * F_OUT; i += 256) sW[i] = W2[i];
    __syncthreads();
    int wave = threadIdx.x >> 6;
    int lane = threadIdx.x & 63;
    int grp = lane >> 4;    // 4 edge groups
    int l4 = lane & 15;     // float4 slot within row (12 used for F1=48)
    int node = blockIdx.x * 4 + wave;
    if (node >= N_NODES) return;
    int r0 = rowptr[node], r1 = rowptr[node + 1];
    float4 acc = make_float4(0.f, 0.f, 0.f, 0.f);
    for (int e = r0 + grp; e < r1; e += 4) {
        int2 ent = csr[e];
        float c = __int_as_float(ent.y);
        if (l4 < 12) {
            float4 v =
                reinterpret_cast<const float4*>(h1 + (size_t)ent.x * F1)[l4];
            acc.x = fmaf(v.x, c, acc.x);
            acc.y = fmaf(v.y, c, acc.y);
            acc.z = fmaf(v.z, c, acc.z);
            acc.w = fmaf(v.w, c, acc.w);
        }
    }
    acc = xor4(acc, 16);
    acc = xor4(acc, 32);
    float di = dinv[node];
    float d2 = di * di;
    float4 x4 = make_float4(0.f, 0.f, 0.f, 0.f);
    if (l4 < 12) {
        float4 hs = reinterpret_cast<const float4*>(h1 + (size_t)node * F1)[l4];
        float4 b4 = reinterpret_cast<const float4*>(b1)[l4];
        x4.x = fmaxf(fmaf(acc.x, di, fmaf(hs.x, d2, b4.x)), 0.f);
        x4.y = fmaxf(fmaf(acc.y, di, fmaf(hs.y, d2, b4.y)), 0.f);
        x4.z = fmaxf(fmaf(acc.z, di, fmaf(hs.z, d2, b4.z)), 0.f);
        x4.w = fmaxf(fmaf(acc.w, di, fmaf(hs.w, d2, b4.w)), 0.f);
    }
    float locv = (lane >= F1) ? loc[node * F_LOC + (lane - F1)] : 0.f;
    float accv = 0.f;
#pragma unroll
    for (int k = 0; k < F1; ++k) {
        float comp = (k & 3) == 0   ? x4.x
                     : (k & 3) == 1 ? x4.y
                     : (k & 3) == 2 ? x4.z
                                    : x4.w;
        float xk = __shfl(comp, k >> 2);
        accv = fmaf(xk, sW[k * F_OUT + lane], accv);
    }
#pragma unroll
    for (int k = F1; k < F_IN2; ++k) {
        float xk = __shfl(locv, k);
        accv = fmaf(xk, sW[k * F_OUT + lane], accv);
    }
    h2[node * F_OUT + lane] = accv;
}

// fused: agg2 (4-edge-group float4 gather) + self + bias -> out
__global__ __launch_bounds__(256) void k_out(
    const float* __restrict__ h2, const float* __restrict__ dinv,
    const int* __restrict__ rowptr, const int2* __restrict__ csr,
    const float* __restrict__ b2, float* __restrict__ out) {
    int wave = threadIdx.x >> 6;
    int lane = threadIdx.x & 63;
    int grp = lane >> 4;
    int l4 = lane & 15;  // all 16 slots used (F_OUT=64)
    int node = blockIdx.x * 4 + wave;
    if (node >= N_NODES) return;
    int r0 = rowptr[node], r1 = rowptr[node + 1];
    float4 acc = make_float4(0.f, 0.f, 0.f, 0.f);
    for (int e = r0 + grp; e < r1; e += 4) {
        int2 ent = csr[e];
        float c = __int_as_float(ent.y);
        float4 v =
            reinterpret_cast<const float4*>(h2 + (size_t)ent.x * F_OUT)[l4];
        acc.x = fmaf(v.x, c, acc.x);
        acc.y = fmaf(v.y, c, acc.y);
        acc.z = fmaf(v.z, c, acc.z);
        acc.w = fmaf(v.w, c, acc.w);
    }
    acc = xor4(acc, 16);
    acc = xor4(acc, 32);
    if (lane < 16) {
        float di = dinv[node];
        float d2 = di * di;
        float4 hs = reinterpret_cast<const float4*>(h2 + (size_t)node * F_OUT)[l4];
        float4 b4 = reinterpret_cast<const float4*>(b2)[l4];
        float4 o;
        o.x = fmaf(acc.x, di, fmaf(hs.x, d2, b4.x));
        o.y = fmaf(acc.y, di, fmaf(hs.y, d2, b4.y));
        o.z = fmaf(acc.z, di, fmaf(hs.z, d2, b4.z));
        o.w = fmaf(acc.w, di, fmaf(hs.w, d2, b4.w));
        reinterpret_cast<float4*>(out + (size_t)node * F_OUT)[l4] = o;
    }
}

extern "C" void kernel_launch(void* const* d_in, const int* in_sizes, int n_in,
                              void* d_out, int out_size, void* d_ws,
                              size_t ws_size, hipStream_t stream) {
    const void* edges = d_in[0];
    const float* feat = (const float*)d_in[1];
    const float* loc = (const float*)d_in[2];
    const float* W1 = (const float*)d_in[3];
    const float* b1 = (const float*)d_in[4];
    const float* W2 = (const float*)d_in[5];
    const float* b2 = (const float*)d_in[6];
    float* out = (float*)d_out;

    char* ws = (char*)d_ws;
    float* dinv = (float*)(ws + 0);         //   400,000
    int* deg = (int*)(ws + 400000);         //   400,000
    int* rowptr = (int*)(ws + 800000);      //   400,016 (incl pad)
    int* cnt = (int*)(ws + 1200016);        //   400,000
    int2* csr = (int2*)(ws + 1600016);      // 10,000,000
    float* h1 = (float*)(ws + 11600016);    // 19,200,000
    float* h2 = (float*)(ws + 30800016);    // 25,600,000
    int* flag = (int*)(ws + 56400016);      // 4
    int* bsum = (int*)(ws + 56400032);      // 392 (scan partials)

    k_detect<<<1, 256, 0, stream>>>((const unsigned*)edges, flag);
    hipMemsetAsync(deg, 0, (size_t)N_NODES * 4, stream);
    k_deg<<<(N_EDGES + 255) / 256, 256, 0, stream>>>(edges, flag, deg);
    k_scan_part<<<SCAN_NB, 256, 0, stream>>>(deg, bsum);
    k_scan_top<<<1, 128, 0, stream>>>(bsum, rowptr);
    k_scan_down<<<SCAN_NB, 256, 0, stream>>>(deg, bsum, rowptr, cnt, dinv);
    k_fill<<<(N_EDGES + 255) / 256, 256, 0, stream>>>(edges, flag, dinv, cnt,
                                                      csr);
    k_h1<<<(N_NODES + 3) / 4, 256, 0, stream>>>(feat, loc, W1, h1);
    k_mid<<<(N_NODES + 3) / 4, 256, 0, stream>>>(h1, dinv, rowptr, csr, loc,
                                                 W2, b1, h2);
    k_out<<<(N_NODES + 3) / 4, 256, 0, stream>>>(h2, dinv, rowptr, csr, b2,
                                                 out);
}